// Round 2
// baseline (1290.741 us; speedup 1.0000x reference)
//
#include <hip/hip_runtime.h>
#include <math.h>

#define NN 50000
#define NE 640000
#define HIDC 128
#define ETILES (NE/16)    // 40000 wave-tiles of 16 edges
#define NTILES ((NN + 63)/64)

typedef short  short8 __attribute__((ext_vector_type(8)));
typedef __bf16 bf16x8 __attribute__((ext_vector_type(8)));
typedef float  f32x4  __attribute__((ext_vector_type(4)));
typedef unsigned int uint2v __attribute__((ext_vector_type(2)));

__device__ __forceinline__ unsigned short f2bf(float f) {
    unsigned int b = __float_as_uint(f);
    b += 0x7FFFu + ((b >> 16) & 1u);          // RTNE
    return (unsigned short)(b >> 16);
}
__device__ __forceinline__ float silu_f(float v) {
    return v / (1.0f + __expf(-v));
}

// ---------------- prep: f32 -> bf16 conversions ----------------
__global__ void conv_x_kernel(const float* __restrict__ x, unsigned short* __restrict__ xb) {
    const int i = blockIdx.x * 256 + threadIdx.x;
    if (i < NN * HIDC) xb[i] = f2bf(x[i]);
}

// weights transposed to [n][k] row-major bf16 so A-fragments are contiguous 16B
__global__ void conv_w_kernel(const float* __restrict__ Wm1, const float* __restrict__ Wm2,
                              const float* __restrict__ Wc1, const float* __restrict__ Wn1,
                              const float* __restrict__ Wn2,
                              unsigned short* __restrict__ wt1, unsigned short* __restrict__ wt2,
                              unsigned short* __restrict__ wtc1, unsigned short* __restrict__ wtn1,
                              unsigned short* __restrict__ wtn2) {
    const int i = blockIdx.x * 256 + threadIdx.x;
    const int C0 = 128 * 288;             // 36864
    if (i < C0) {
        const int n = i / 288, k = i % 288;
        wt1[i] = (k < 260) ? f2bf(Wm1[k * 128 + n]) : (unsigned short)0;
    } else if (i < C0 + 16384) {
        const int j = i - C0; const int n = j >> 7, k = j & 127;
        wt2[j] = f2bf(Wm2[k * 128 + n]);
    } else if (i < C0 + 2 * 16384) {
        const int j = i - C0 - 16384; const int n = j >> 7, k = j & 127;
        wtc1[j] = f2bf(Wc1[k * 128 + n]);
    } else if (i < C0 + 2 * 16384 + 32768) {
        const int j = i - C0 - 2 * 16384; const int n = j >> 8, k = j & 255;
        wtn1[j] = f2bf(Wn1[k * 128 + n]);
    } else if (i < C0 + 2 * 16384 + 32768 + 16384) {
        const int j = i - C0 - 2 * 16384 - 32768; const int n = j >> 7, k = j & 127;
        wtn2[j] = f2bf(Wn2[k * 128 + n]);
    }
}

// ---------------- fused edge kernel (barrier-free, wave-independent) ----------------
// 1024 threads = 16 waves; each wave owns 16 edges per tile, fully independent.
// Swapped orientation: compute h^T = W1^T * msg_input^T etc.
//   A-operand = weight rows (hid) from LDS (XOR-swizzled granules),
//   B-operand = gathered node features, direct global->VGPR (16B per lane).
// C/D layout (verified): col = lane&15 = edge, row = (lane>>4)*4+q = hid-in-tile.
__launch_bounds__(1024)
__global__ void edge_kernel(
    const unsigned short* __restrict__ xb, const float* __restrict__ pos,
    const int* __restrict__ ei, const float* __restrict__ eattr,
    const unsigned short* __restrict__ wt1g, const unsigned short* __restrict__ wt2g,
    const unsigned short* __restrict__ wtc1g, const float* __restrict__ Wm1,
    const float* __restrict__ bm1v, const float* __restrict__ bm2v,
    const float* __restrict__ bc1v, const float* __restrict__ wc2v,
    const float* __restrict__ bc2v,
    float* __restrict__ agg, float* __restrict__ cagg)
{
    // 122880 B total LDS
    __shared__ __align__(16) unsigned short wt1L[128][256];   // W1^T k=0..255, 65536 B
    __shared__ __align__(16) unsigned short wt2L[128][128];   // 32768 B
    __shared__ __align__(16) float cons[8][128];              // bm1,bm2,bc1,wc2,W1[256..259][:]
    __shared__ __align__(16) unsigned short ring[16][16][40]; // per-wave h/msg staging, 20480 B

    const int tid = threadIdx.x;
    const int wid = tid >> 6;
    const int lane = tid & 63;
    const int c  = lane & 15;      // edge-in-tile (B col) AND weight-row low bits (A row)
    const int g  = lane >> 4;      // k-chunk group
    const int c7 = c & 7;
    const f32x4 z4 = {0.f, 0.f, 0.f, 0.f};

    // ---- one-time LDS fill (the only barrier in this kernel) ----
    #pragma unroll
    for (int i = tid; i < 4096; i += 1024) {
        const int n = i >> 5, G = i & 31;
        *reinterpret_cast<short8*>(&wt1L[n][(G ^ (n & 7)) << 3]) =
            *reinterpret_cast<const short8*>(wt1g + n * 288 + (G << 3));
    }
    #pragma unroll
    for (int i = tid; i < 2048; i += 1024) {
        const int n = i >> 4, G = i & 15;
        *reinterpret_cast<short8*>(&wt2L[n][(G ^ (n & 7)) << 3]) =
            *reinterpret_cast<const short8*>(wt2g + n * 128 + (G << 3));
    }
    {
        const int r = tid >> 7, j = tid & 127;   // 1024 = 8*128 exactly
        cons[r][j] = (r == 0) ? bm1v[j] : (r == 1) ? bm2v[j] : (r == 2) ? bc1v[j]
                   : (r == 3) ? wc2v[j] : Wm1[(256 + (r - 4)) * 128 + j];
    }
    const float bc2s = bc2v[0];
    __syncthreads();

    const int gw = blockIdx.x * 16 + wid;        // global wave id, 4096 total

    for (int t = gw; t < ETILES; t += 4096) {
        const int e = (t << 4) + c;
        const int s = ei[e];
        const int d = ei[NE + e];
        const float dx = pos[s*3+0] - pos[d*3+0];
        const float dy = pos[s*3+1] - pos[d*3+1];
        const float dz = pos[s*3+2] - pos[d*3+2];
        const float dist = sqrtf(dx*dx + dy*dy + dz*dz);
        const float ea0 = eattr[e*3+0];
        const float ea1 = eattr[e*3+1];
        const float ea2 = eattr[e*3+2];

        // gather B-fragments: full src/dst feature rows, 16B per lane per chunk
        bf16x8 bf[8];
        const size_t sbase = (size_t)s * HIDC;
        const size_t dbase = (size_t)d * HIDC;
        #pragma unroll
        for (int kk = 0; kk < 4; ++kk) {
            bf[kk]     = *reinterpret_cast<const bf16x8*>(xb + sbase + kk*32 + g*8);
            bf[kk + 4] = *reinterpret_cast<const bf16x8*>(xb + dbase + kk*32 + g*8);
        }

        // ---- GEMM1 (h^T) with GEMM2 (msg^T) interleaved under it ----
        f32x4 acc2[8] = {z4, z4, z4, z4, z4, z4, z4, z4};
        #pragma unroll
        for (int mt = 0; mt < 8; ++mt) {
            f32x4 a1 = z4;
            #pragma unroll
            for (int kk = 0; kk < 8; ++kk) {
                const bf16x8 aw = *reinterpret_cast<const bf16x8*>(
                    &wt1L[16*mt + c][(((kk << 2) + g) ^ c7) << 3]);
                a1 = __builtin_amdgcn_mfma_f32_16x16x32_bf16(aw, bf[kk], a1, 0, 0, 0);
            }
            {   // rank-4 update (dist + edge_attr columns of W1), bias, silu, stage
                const int hb = 16*mt + 4*g;
                const f32x4 w0 = *reinterpret_cast<const f32x4*>(&cons[4][hb]);
                const f32x4 w1 = *reinterpret_cast<const f32x4*>(&cons[5][hb]);
                const f32x4 w2 = *reinterpret_cast<const f32x4*>(&cons[6][hb]);
                const f32x4 w3 = *reinterpret_cast<const f32x4*>(&cons[7][hb]);
                const f32x4 bq = *reinterpret_cast<const f32x4*>(&cons[0][hb]);
                float h[4];
                #pragma unroll
                for (int q = 0; q < 4; ++q)
                    h[q] = silu_f(a1[q] + dist*w0[q] + ea0*w1[q] + ea1*w2[q] + ea2*w3[q] + bq[q]);
                uint2v u;
                u[0] = (unsigned)f2bf(h[0]) | ((unsigned)f2bf(h[1]) << 16);
                u[1] = (unsigned)f2bf(h[2]) | ((unsigned)f2bf(h[3]) << 16);
                *reinterpret_cast<uint2v*>(&ring[wid][c][(mt & 1) * 16 + 4*g]) = u;
            }
            if (mt & 1) {
                const int kk2 = mt >> 1;
                const bf16x8 hf = *reinterpret_cast<const bf16x8*>(&ring[wid][c][g << 3]);
                #pragma unroll
                for (int mo = 0; mo < 8; ++mo) {
                    const bf16x8 a2 = *reinterpret_cast<const bf16x8*>(
                        &wt2L[16*mo + c][(((kk2 << 2) + g) ^ c7) << 3]);
                    acc2[mo] = __builtin_amdgcn_mfma_f32_16x16x32_bf16(a2, hf, acc2[mo], 0, 0, 0);
                }
            }
        }

        // ---- GEMM2 epilogue (silu, agg atomics, stage msg) + GEMM3 (c^T) interleaved ----
        f32x4 acc3[8] = {z4, z4, z4, z4, z4, z4, z4, z4};
        #pragma unroll
        for (int kkc = 0; kkc < 4; ++kkc) {
            #pragma unroll
            for (int half = 0; half < 2; ++half) {
                const int mt2 = 2*kkc + half;
                const int hb = 16*mt2 + 4*g;
                const f32x4 bq = *reinterpret_cast<const f32x4*>(&cons[1][hb]);
                float m[4];
                #pragma unroll
                for (int q = 0; q < 4; ++q) {
                    m[q] = silu_f(acc2[mt2][q] + bq[q]);
                    atomicAdd(&agg[(size_t)s * HIDC + hb + q], m[q]);
                }
                uint2v u;
                u[0] = (unsigned)f2bf(m[0]) | ((unsigned)f2bf(m[1]) << 16);
                u[1] = (unsigned)f2bf(m[2]) | ((unsigned)f2bf(m[3]) << 16);
                *reinterpret_cast<uint2v*>(&ring[wid][c][half * 16 + 4*g]) = u;
            }
            const bf16x8 mf = *reinterpret_cast<const bf16x8*>(&ring[wid][c][g << 3]);
            #pragma unroll
            for (int mo = 0; mo < 8; ++mo) {
                const bf16x8 a3 = *reinterpret_cast<const bf16x8*>(
                    wtc1g + (size_t)(16*mo + c) * HIDC + kkc*32 + g*8);
                acc3[mo] = __builtin_amdgcn_mfma_f32_16x16x32_bf16(a3, mf, acc3[mo], 0, 0, 0);
            }
        }

        // ---- coord_w = Wc2 . silu(c) + bc2, reduce over hid, coord atomics ----
        float cw = 0.f;
        #pragma unroll
        for (int mt = 0; mt < 8; ++mt) {
            const int hb = 16*mt + 4*g;
            const f32x4 bq = *reinterpret_cast<const f32x4*>(&cons[2][hb]);
            const f32x4 wq = *reinterpret_cast<const f32x4*>(&cons[3][hb]);
            #pragma unroll
            for (int q = 0; q < 4; ++q)
                cw += silu_f(acc3[mt][q] + bq[q]) * wq[q];
        }
        cw += __shfl_xor(cw, 16, 64);
        cw += __shfl_xor(cw, 32, 64);
        cw += bc2s;
        if (g == 0) {
            atomicAdd(&cagg[s*3+0], dx * cw);
            atomicAdd(&cagg[s*3+1], dy * cw);
            atomicAdd(&cagg[s*3+2], dz * cw);
        }
    }
}

// ---------------- node kernel: x_new + pos_new ----------------
__launch_bounds__(512, 4)
__global__ void node_kernel(
    const unsigned short* __restrict__ xb, const float* __restrict__ agg,
    const unsigned short* __restrict__ wtn1, const unsigned short* __restrict__ wtn2,
    const float* __restrict__ bn1v, const float* __restrict__ bn2v,
    const float* __restrict__ pos, const float* __restrict__ cagg,
    float* __restrict__ outx, float* __restrict__ outp)
{
    __shared__ __align__(16) unsigned short AN[64][256];   // [x | agg] bf16, swizzled
    __shared__ __align__(16) unsigned short HN[64][128];
    const int tid = threadIdx.x;
    const int lane = tid & 63;
    const int wid = tid >> 6;
    const int lr = lane & 15;
    const int lg = lane >> 4;
    const int mycol = wid * 16 + lr;
    const float bn1_l = bn1v[mycol];
    const float bn2_l = bn2v[mycol];
    const f32x4 z4 = {0.f, 0.f, 0.f, 0.f};
    const int n0 = blockIdx.x * 64;

    {
        const int i = tid >> 3, j = tid & 7;
        const int n = n0 + i;
        const bool ok = (n < NN);
        #pragma unroll
        for (int gi = 0; gi < 4; ++gi) {
            const int g = j + gi * 8;          // 0..31
            unsigned short* dp = &AN[i][0] + (((g ^ (i & 7))) << 3);
            short8 v = {0,0,0,0,0,0,0,0};
            if (ok) {
                if (g < 16) {
                    v = *reinterpret_cast<const short8*>(xb + (size_t)n * HIDC + (g << 3));
                } else {
                    const float* ap = agg + (size_t)n * HIDC + ((g - 16) << 3);
                    #pragma unroll
                    for (int cc = 0; cc < 8; ++cc) v[cc] = (short)f2bf(ap[cc]);
                }
            }
            *reinterpret_cast<short8*>(dp) = v;
        }
    }
    __syncthreads();

    f32x4 acc[4] = {z4, z4, z4, z4};
    #pragma unroll
    for (int kk = 0; kk < 8; ++kk) {
        const bf16x8 b = *reinterpret_cast<const bf16x8*>(wtn1 + (size_t)mycol * 256 + kk * 32 + lg * 8);
        #pragma unroll
        for (int m = 0; m < 4; ++m) {
            const int r = m * 16 + lr;
            const int g = (kk * 4 + lg) ^ (r & 7);
            const bf16x8 a = *reinterpret_cast<const bf16x8*>(&AN[r][0] + (g << 3));
            acc[m] = __builtin_amdgcn_mfma_f32_16x16x32_bf16(a, b, acc[m], 0, 0, 0);
        }
    }
    #pragma unroll
    for (int m = 0; m < 4; ++m) {
        #pragma unroll
        for (int q = 0; q < 4; ++q) {
            const int r = m * 16 + lg * 4 + q;
            HN[r][mycol ^ ((r & 7) << 3)] = f2bf(silu_f(acc[m][q] + bn1_l));
        }
    }
    __syncthreads();

    f32x4 acc2[4] = {z4, z4, z4, z4};
    #pragma unroll
    for (int kk = 0; kk < 4; ++kk) {
        const bf16x8 b = *reinterpret_cast<const bf16x8*>(wtn2 + (size_t)mycol * HIDC + kk * 32 + lg * 8);
        #pragma unroll
        for (int m = 0; m < 4; ++m) {
            const int r = m * 16 + lr;
            const int g = (kk * 4 + lg) ^ (r & 7);
            const bf16x8 a = *reinterpret_cast<const bf16x8*>(&HN[r][0] + (g << 3));
            acc2[m] = __builtin_amdgcn_mfma_f32_16x16x32_bf16(a, b, acc2[m], 0, 0, 0);
        }
    }
    #pragma unroll
    for (int m = 0; m < 4; ++m) {
        #pragma unroll
        for (int q = 0; q < 4; ++q) {
            const int n = n0 + m * 16 + lg * 4 + q;
            if (n < NN) outx[(size_t)n * HIDC + mycol] = acc2[m][q] + bn2_l;
        }
    }
    if (tid < 192) {
        const int r = n0 + tid / 3;
        const int d2 = tid - (tid / 3) * 3;
        if (r < NN) outp[r * 3 + d2] = pos[r * 3 + d2] + cagg[r * 3 + d2];
    }
}

// ---------------- launch ----------------
extern "C" void kernel_launch(void* const* d_in, const int* in_sizes, int n_in,
                              void* d_out, int out_size, void* d_ws, size_t ws_size,
                              hipStream_t stream)
{
    const float* x   = (const float*)d_in[0];
    const float* pos = (const float*)d_in[1];
    const int*   ei  = (const int*)d_in[2];
    const float* ea  = (const float*)d_in[3];
    const float* Wm1 = (const float*)d_in[4];
    const float* bm1 = (const float*)d_in[5];
    const float* Wm2 = (const float*)d_in[6];
    const float* bm2 = (const float*)d_in[7];
    const float* Wn1 = (const float*)d_in[8];
    const float* bn1 = (const float*)d_in[9];
    const float* Wn2 = (const float*)d_in[10];
    const float* bn2 = (const float*)d_in[11];
    const float* Wc1 = (const float*)d_in[12];
    const float* bc1 = (const float*)d_in[13];
    const float* Wc2 = (const float*)d_in[14];
    const float* bc2 = (const float*)d_in[15];

    // workspace layout (bytes); total ~39.3 MB
    char* ws = (char*)d_ws;
    unsigned short* xb   = (unsigned short*)(ws);              // 12,800,000
    float* agg           = (float*)(ws + 12800000);            // 25,600,000
    float* cagg          = (float*)(ws + 38400000);            //    600,000
    unsigned short* wt1  = (unsigned short*)(ws + 39000000);   //     73,728
    unsigned short* wt2  = (unsigned short*)(ws + 39073728);   //     32,768
    unsigned short* wtc1 = (unsigned short*)(ws + 39106496);   //     32,768
    unsigned short* wtn1 = (unsigned short*)(ws + 39139264);   //     65,536
    unsigned short* wtn2 = (unsigned short*)(ws + 39204800);   //     32,768

    float* outx = (float*)d_out;
    float* outp = outx + (size_t)NN * HIDC;

    hipMemsetAsync(agg, 0, (size_t)NN * HIDC * sizeof(float), stream);
    hipMemsetAsync(cagg, 0, (size_t)NN * 3 * sizeof(float), stream);
    conv_x_kernel<<<(NN * HIDC + 255) / 256, 256, 0, stream>>>(x, xb);
    conv_w_kernel<<<(118784 + 255) / 256, 256, 0, stream>>>(Wm1, Wm2, Wc1, Wn1, Wn2,
                                                            wt1, wt2, wtc1, wtn1, wtn2);
    edge_kernel<<<256, 1024, 0, stream>>>(xb, pos, ei, ea, wt1, wt2, wtc1, Wm1,
                                          bm1, bm2, bc1, Wc2, bc2, agg, cagg);
    node_kernel<<<NTILES, 512, 0, stream>>>(xb, agg, wtn1, wtn2, bn1, bn2, pos, cagg, outx, outp);
}

// Round 3
// 574.181 us; speedup vs baseline: 2.2480x; 2.2480x over previous
//
#include <hip/hip_runtime.h>
#include <math.h>

#define NN 50000
#define NE 640000
#define HIDC 128
#define ETILES 10000          // NE/64
#define NTILES ((NN + 63)/64)

typedef short  short8 __attribute__((ext_vector_type(8)));
typedef __bf16 bf16x8 __attribute__((ext_vector_type(8)));
typedef float  f32x4  __attribute__((ext_vector_type(4)));

__device__ __forceinline__ unsigned short f2bf(float f) {
    unsigned int b = __float_as_uint(f);
    b += 0x7FFFu + ((b >> 16) & 1u);          // RTNE
    return (unsigned short)(b >> 16);
}
__device__ __forceinline__ float silu_f(float v) {
    return v / (1.0f + __expf(-v));
}

// ---------------- prep: f32 -> bf16 conversions ----------------
__global__ void conv_x_kernel(const float* __restrict__ x, unsigned short* __restrict__ xb) {
    const int i = blockIdx.x * 256 + threadIdx.x;
    if (i < NN * HIDC) xb[i] = f2bf(x[i]);
}

// weights transposed to [n][k] row-major bf16 (wt1/wtn1 K=256, others K=128)
__global__ void conv_w_kernel(const float* __restrict__ Wm1, const float* __restrict__ Wm2,
                              const float* __restrict__ Wc1, const float* __restrict__ Wn1,
                              const float* __restrict__ Wn2,
                              unsigned short* __restrict__ wt1, unsigned short* __restrict__ wt2,
                              unsigned short* __restrict__ wtc1, unsigned short* __restrict__ wtn1,
                              unsigned short* __restrict__ wtn2) {
    const int i = blockIdx.x * 256 + threadIdx.x;
    if (i < 32768) {
        const int n = i >> 8, k = i & 255;
        wt1[i] = f2bf(Wm1[k * 128 + n]);                 // only k<256; k=256..259 via cons
    } else if (i < 49152) {
        const int j = i - 32768; const int n = j >> 7, k = j & 127;
        wt2[j] = f2bf(Wm2[k * 128 + n]);
    } else if (i < 65536) {
        const int j = i - 49152; const int n = j >> 7, k = j & 127;
        wtc1[j] = f2bf(Wc1[k * 128 + n]);
    } else if (i < 98304) {
        const int j = i - 65536; const int n = j >> 8, k = j & 255;
        wtn1[j] = f2bf(Wn1[k * 128 + n]);
    } else if (i < 114688) {
        const int j = i - 98304; const int n = j >> 7, k = j & 127;
        wtn2[j] = f2bf(Wn2[k * 128 + n]);
    }
}

// ---------------- CSR build ----------------
__global__ void count_kernel(const int* __restrict__ ei, int* __restrict__ cnt) {
    const int e = blockIdx.x * 256 + threadIdx.x;
    if (e < NE) atomicAdd(&cnt[ei[e]], 1);
}

__global__ void scan_kernel(const int* __restrict__ cnt, int* __restrict__ offs,
                            int* __restrict__ offs2) {
    __shared__ int wtot[16];
    const int t = threadIdx.x, lane = t & 63, wid = t >> 6;
    const int base = t * 49;                 // 1024*49 = 50176 >= NN
    int s = 0;
    for (int i = 0; i < 49; ++i) { const int idx = base + i; if (idx < NN) s += cnt[idx]; }
    int inc = s;
    for (int d = 1; d < 64; d <<= 1) { int u = __shfl_up(inc, d, 64); if (lane >= d) inc += u; }
    if (lane == 63) wtot[wid] = inc;
    __syncthreads();
    if (t == 0) { int a = 0; for (int w = 0; w < 16; ++w) { int v = wtot[w]; wtot[w] = a; a += v; } }
    __syncthreads();
    int pre = wtot[wid] + inc - s;
    for (int i = 0; i < 49; ++i) {
        const int idx = base + i;
        if (idx < NN) { offs[idx] = pre; offs2[idx] = pre; pre += cnt[idx]; }
    }
}

__global__ void scatter_kernel(const int* __restrict__ ei, int* __restrict__ offs2,
                               int* __restrict__ slot) {
    const int e = blockIdx.x * 256 + threadIdx.x;
    if (e < NE) slot[e] = atomicAdd(&offs2[ei[e]], 1);
}

// ---------------- fused edge kernel ----------------
// 512 threads = 8 waves; 64-edge tile; wave w owns output cols [16w,16w+16).
// 4 barriers/tile. CSR mode: msg -> msgb[slot], wdiff -> wdiffv[slot] (no atomics).
// Fallback mode: f32 atomics with row-local lane pattern (round-1 scheme).
template <bool CSR>
__launch_bounds__(512, 4)
__global__ void edge_kernel(
    const unsigned short* __restrict__ xb, const float* __restrict__ pos,
    const int* __restrict__ ei, const float* __restrict__ eattr,
    const unsigned short* __restrict__ wt1, const unsigned short* __restrict__ wt2,
    const unsigned short* __restrict__ wtc1, const float* __restrict__ Wm1,
    const float* __restrict__ bm1v, const float* __restrict__ bm2v,
    const float* __restrict__ bc1v, const float* __restrict__ wc2v,
    const float* __restrict__ bc2v, const int* __restrict__ slot,
    unsigned short* __restrict__ msgb, float* __restrict__ wdiffv,
    float* __restrict__ agg, float* __restrict__ cagg)
{
    __shared__ __align__(16) unsigned short A1[64][256];   // 32 KB msg_input (k<256)
    __shared__ __align__(16) unsigned short H2[64][HIDC];  // 16 KB
    __shared__ __align__(16) unsigned short M3[64][HIDC];  // 16 KB
    __shared__ __align__(16) float cons[8][128];           // bm1,bm2,bc1,wc2,W1[256..259]
    __shared__ __align__(16) float DIFX[64][8];            // dx,dy,dz,dist,ea0,ea1,ea2,pad
    __shared__ float CW[8][64];
    __shared__ int   SLT[64];                              // CSR slot (or SRC in fallback)

    const int tid = threadIdx.x;
    const int lane = tid & 63;
    const int wid = tid >> 6;
    const int lr = lane & 15;
    const int lg = lane >> 4;
    const int mycol = wid * 16 + lr;
    const f32x4 z4 = {0.f, 0.f, 0.f, 0.f};

    for (int i = tid; i < 1024; i += 512) {
        const int r = i >> 7, j = i & 127;
        cons[r][j] = (r == 0) ? bm1v[j] : (r == 1) ? bm2v[j] : (r == 2) ? bc1v[j]
                   : (r == 3) ? wc2v[j] : Wm1[(256 + (r - 4)) * 128 + j];
    }
    __syncthreads();
    const float bm1_l = cons[0][mycol], bm2_l = cons[1][mycol];
    const float bc1_l = cons[2][mycol], wc2_l = cons[3][mycol];
    const float wk0 = cons[4][mycol], wk1 = cons[5][mycol];
    const float wk2 = cons[6][mycol], wk3 = cons[7][mycol];
    const float bc2s = bc2v[0];

    for (int tile = blockIdx.x; tile < ETILES; tile += gridDim.x) {
        const int e0 = tile << 6;
        { // build phase (self-sufficient; no intra-phase dependencies)
            const int bi = tid >> 3, bj = tid & 7;
            const int e = e0 + bi;
            const int s = ei[e], d = ei[NE + e];
            const unsigned short* sr = xb + (size_t)s * HIDC;
            const unsigned short* dr = xb + (size_t)d * HIDC;
            unsigned short* arow = &A1[bi][0];
            #pragma unroll
            for (int gi = 0; gi < 4; ++gi) {
                const int g = bj + gi * 8;                 // 0..31
                const unsigned short* src = (g < 16) ? (sr + (g << 3)) : (dr + ((g - 16) << 3));
                *reinterpret_cast<short8*>(arow + ((g ^ (bi & 7)) << 3)) =
                    *reinterpret_cast<const short8*>(src);
            }
            if (tid < 64) {
                const int e2 = e0 + tid;
                const int s2 = ei[e2], d2 = ei[NE + e2];
                const float dx = pos[s2*3+0] - pos[d2*3+0];
                const float dy = pos[s2*3+1] - pos[d2*3+1];
                const float dz = pos[s2*3+2] - pos[d2*3+2];
                DIFX[tid][0] = dx; DIFX[tid][1] = dy; DIFX[tid][2] = dz;
                DIFX[tid][3] = sqrtf(dx*dx + dy*dy + dz*dz);
                DIFX[tid][4] = eattr[e2*3+0];
                DIFX[tid][5] = eattr[e2*3+1];
                DIFX[tid][6] = eattr[e2*3+2];
                SLT[tid] = CSR ? slot[e2] : s2;
            }
        }
        __syncthreads();                                   // b1: A1/DIFX/SLT ready

        // GEMM1: [64,256] @ W1^T + rank-4 update (dist, edge_attr), SiLU -> H2
        f32x4 acc[4] = {z4, z4, z4, z4};
        #pragma unroll
        for (int kk = 0; kk < 8; ++kk) {
            const bf16x8 b = *reinterpret_cast<const bf16x8*>(wt1 + mycol * 256 + kk * 32 + lg * 8);
            #pragma unroll
            for (int m = 0; m < 4; ++m) {
                const int r = m * 16 + lr;
                const bf16x8 a = *reinterpret_cast<const bf16x8*>(
                    &A1[r][0] + (((kk * 4 + lg) ^ (r & 7)) << 3));
                acc[m] = __builtin_amdgcn_mfma_f32_16x16x32_bf16(a, b, acc[m], 0, 0, 0);
            }
        }
        #pragma unroll
        for (int m = 0; m < 4; ++m) {
            #pragma unroll
            for (int q = 0; q < 4; ++q) {
                const int r = m * 16 + lg * 4 + q;
                const f32x4 d0 = *reinterpret_cast<const f32x4*>(&DIFX[r][0]);
                const f32x4 d1 = *reinterpret_cast<const f32x4*>(&DIFX[r][4]);
                const float h = acc[m][q] + d0[3]*wk0 + d1[0]*wk1 + d1[1]*wk2 + d1[2]*wk3 + bm1_l;
                H2[r][mycol ^ ((r & 7) << 3)] = f2bf(silu_f(h));
            }
        }
        __syncthreads();                                   // b2: H2 ready

        // GEMM2: h @ W2^T, SiLU -> M3 (+ atomics in fallback mode)
        f32x4 acc2[4] = {z4, z4, z4, z4};
        #pragma unroll
        for (int kk = 0; kk < 4; ++kk) {
            const bf16x8 b = *reinterpret_cast<const bf16x8*>(wt2 + mycol * 128 + kk * 32 + lg * 8);
            #pragma unroll
            for (int m = 0; m < 4; ++m) {
                const int r = m * 16 + lr;
                const bf16x8 a = *reinterpret_cast<const bf16x8*>(
                    &H2[r][0] + (((kk * 4 + lg) ^ (r & 7)) << 3));
                acc2[m] = __builtin_amdgcn_mfma_f32_16x16x32_bf16(a, b, acc2[m], 0, 0, 0);
            }
        }
        #pragma unroll
        for (int m = 0; m < 4; ++m) {
            #pragma unroll
            for (int q = 0; q < 4; ++q) {
                const int r = m * 16 + lg * 4 + q;
                const float mv = silu_f(acc2[m][q] + bm2_l);
                M3[r][mycol ^ ((r & 7) << 3)] = f2bf(mv);
                if (!CSR) atomicAdd(&agg[(size_t)SLT[r] * HIDC + mycol], mv);
            }
        }
        __syncthreads();                                   // b3: M3 ready

        // GEMM3: msg @ Wc1^T -> t; cw = Wc2 . silu(t); msg copy-out (CSR)
        f32x4 acc3[4] = {z4, z4, z4, z4};
        #pragma unroll
        for (int kk = 0; kk < 4; ++kk) {
            const bf16x8 b = *reinterpret_cast<const bf16x8*>(wtc1 + mycol * 128 + kk * 32 + lg * 8);
            #pragma unroll
            for (int m = 0; m < 4; ++m) {
                const int r = m * 16 + lr;
                const bf16x8 a = *reinterpret_cast<const bf16x8*>(
                    &M3[r][0] + (((kk * 4 + lg) ^ (r & 7)) << 3));
                acc3[m] = __builtin_amdgcn_mfma_f32_16x16x32_bf16(a, b, acc3[m], 0, 0, 0);
            }
        }
        #pragma unroll
        for (int m = 0; m < 4; ++m) {
            #pragma unroll
            for (int q = 0; q < 4; ++q) {
                float tv = silu_f(acc3[m][q] + bc1_l) * wc2_l;
                tv += __shfl_xor(tv, 1, 64);
                tv += __shfl_xor(tv, 2, 64);
                tv += __shfl_xor(tv, 4, 64);
                tv += __shfl_xor(tv, 8, 64);
                if (lr == 0) CW[wid][m * 16 + lg * 4 + q] = tv;
            }
        }
        if (CSR) {  // coalesced msg write-out to CSR slot rows
            const int i2 = tid >> 3, j2 = tid & 7;
            const size_t ob = (size_t)SLT[i2] * HIDC;
            #pragma unroll
            for (int gi = 0; gi < 2; ++gi) {
                const int g = j2 + gi * 8;                 // 0..15
                const short8 v = *reinterpret_cast<const short8*>(
                    &M3[i2][0] + ((g ^ (i2 & 7)) << 3));
                *reinterpret_cast<short8*>(msgb + ob + (g << 3)) = v;
            }
        }
        __syncthreads();                                   // b4: CW ready

        if (tid < 64) {
            float s = bc2s;
            #pragma unroll
            for (int w = 0; w < 8; ++w) s += CW[w][tid];
            if (CSR) {
                const size_t wb = (size_t)SLT[tid] * 4;
                wdiffv[wb + 0] = DIFX[tid][0] * s;
                wdiffv[wb + 1] = DIFX[tid][1] * s;
                wdiffv[wb + 2] = DIFX[tid][2] * s;
            } else {
                const int sn = SLT[tid];
                atomicAdd(&cagg[sn * 3 + 0], DIFX[tid][0] * s);
                atomicAdd(&cagg[sn * 3 + 1], DIFX[tid][1] * s);
                atomicAdd(&cagg[sn * 3 + 2], DIFX[tid][2] * s);
            }
        }
    }
}

// ---------------- node kernel: aggregation (CSR) + node MLP + pos_new ----------------
template <bool CSR>
__launch_bounds__(512, 4)
__global__ void node_kernel(
    const unsigned short* __restrict__ xb,
    const unsigned short* __restrict__ msgb, const float* __restrict__ wdiffv,
    const int* __restrict__ offs, const int* __restrict__ cnt,
    const float* __restrict__ agg, const float* __restrict__ cagg,
    const unsigned short* __restrict__ wtn1, const unsigned short* __restrict__ wtn2,
    const float* __restrict__ bn1v, const float* __restrict__ bn2v,
    const float* __restrict__ pos,
    float* __restrict__ outx, float* __restrict__ outp)
{
    __shared__ __align__(16) unsigned short AN[64][256];
    __shared__ __align__(16) unsigned short HN[64][HIDC];
    const int tid = threadIdx.x;
    const int lane = tid & 63;
    const int wid = tid >> 6;
    const int lr = lane & 15;
    const int lg = lane >> 4;
    const int mycol = wid * 16 + lr;
    const float bn1_l = bn1v[mycol];
    const float bn2_l = bn2v[mycol];
    const f32x4 z4 = {0.f, 0.f, 0.f, 0.f};
    const int n0 = blockIdx.x * 64;

    { // x half of AN (granules 0..15)
        const int i = tid >> 3, j = tid & 7;
        const int n = n0 + i;
        const bool ok = (n < NN);
        #pragma unroll
        for (int gi = 0; gi < 2; ++gi) {
            const int g = j + gi * 8;
            short8 v = {0,0,0,0,0,0,0,0};
            if (ok) v = *reinterpret_cast<const short8*>(xb + (size_t)n * HIDC + (g << 3));
            *reinterpret_cast<short8*>(&AN[i][0] + ((g ^ (i & 7)) << 3)) = v;
        }
    }
    if (CSR) { // per-wave CSR aggregation: 8 nodes per wave, contiguous slab reads
        const int r4 = lane >> 4;
        const int cb = (lane & 15) << 3;
        const int cc = lane & 3;
        for (int s = 0; s < 8; ++s) {
            const int n = n0 + wid * 8 + s;
            if (n >= NN) break;
            const int beg = offs[n], deg = cnt[n];
            float a[8] = {0,0,0,0,0,0,0,0};
            float wsum = 0.f;
            for (int p = beg + r4; p < beg + deg; p += 4) {
                const bf16x8 v = *reinterpret_cast<const bf16x8*>(msgb + (size_t)p * HIDC + cb);
                #pragma unroll
                for (int j = 0; j < 8; ++j) a[j] += (float)v[j];
                wsum += wdiffv[(size_t)p * 4 + cc];
            }
            #pragma unroll
            for (int j = 0; j < 8; ++j) {
                a[j] += __shfl_xor(a[j], 16, 64);
                a[j] += __shfl_xor(a[j], 32, 64);
            }
            wsum += __shfl_xor(wsum, 16, 64);
            wsum += __shfl_xor(wsum, 32, 64);
            const int i = wid * 8 + s;
            if (lane < 16) {
                short8 pv;
                #pragma unroll
                for (int j = 0; j < 8; ++j) pv[j] = (short)f2bf(a[j]);
                *reinterpret_cast<short8*>(&AN[i][0] + (((16 + lane) ^ (i & 7)) << 3)) = pv;
            }
            if (lane < 3) outp[(size_t)n * 3 + lane] = pos[n * 3 + lane] + wsum;
        }
    } else { // fallback: agg from global f32
        const int i = tid >> 3, j = tid & 7;
        const int n = n0 + i;
        const bool ok = (n < NN);
        #pragma unroll
        for (int gi = 2; gi < 4; ++gi) {
            const int g = j + gi * 8;                      // 16..31
            short8 v = {0,0,0,0,0,0,0,0};
            if (ok) {
                const float* ap = agg + (size_t)n * HIDC + ((g - 16) << 3);
                #pragma unroll
                for (int c = 0; c < 8; ++c) v[c] = (short)f2bf(ap[c]);
            }
            *reinterpret_cast<short8*>(&AN[i][0] + ((g ^ (i & 7)) << 3)) = v;
        }
        if (tid < 192) {
            const int r = n0 + tid / 3;
            const int d2 = tid - (tid / 3) * 3;
            if (r < NN) outp[r * 3 + d2] = pos[r * 3 + d2] + cagg[r * 3 + d2];
        }
    }
    __syncthreads();

    f32x4 acc[4] = {z4, z4, z4, z4};
    #pragma unroll
    for (int kk = 0; kk < 8; ++kk) {
        const bf16x8 b = *reinterpret_cast<const bf16x8*>(wtn1 + mycol * 256 + kk * 32 + lg * 8);
        #pragma unroll
        for (int m = 0; m < 4; ++m) {
            const int r = m * 16 + lr;
            const bf16x8 a = *reinterpret_cast<const bf16x8*>(
                &AN[r][0] + (((kk * 4 + lg) ^ (r & 7)) << 3));
            acc[m] = __builtin_amdgcn_mfma_f32_16x16x32_bf16(a, b, acc[m], 0, 0, 0);
        }
    }
    #pragma unroll
    for (int m = 0; m < 4; ++m) {
        #pragma unroll
        for (int q = 0; q < 4; ++q) {
            const int r = m * 16 + lg * 4 + q;
            HN[r][mycol ^ ((r & 7) << 3)] = f2bf(silu_f(acc[m][q] + bn1_l));
        }
    }
    __syncthreads();

    f32x4 acc2[4] = {z4, z4, z4, z4};
    #pragma unroll
    for (int kk = 0; kk < 4; ++kk) {
        const bf16x8 b = *reinterpret_cast<const bf16x8*>(wtn2 + mycol * 128 + kk * 32 + lg * 8);
        #pragma unroll
        for (int m = 0; m < 4; ++m) {
            const int r = m * 16 + lr;
            const bf16x8 a = *reinterpret_cast<const bf16x8*>(
                &HN[r][0] + (((kk * 4 + lg) ^ (r & 7)) << 3));
            acc2[m] = __builtin_amdgcn_mfma_f32_16x16x32_bf16(a, b, acc2[m], 0, 0, 0);
        }
    }
    #pragma unroll
    for (int m = 0; m < 4; ++m) {
        #pragma unroll
        for (int q = 0; q < 4; ++q) {
            const int n = n0 + m * 16 + lg * 4 + q;
            if (n < NN) outx[(size_t)n * HIDC + mycol] = acc2[m][q] + bn2_l;
        }
    }
}

// ---------------- launch ----------------
extern "C" void kernel_launch(void* const* d_in, const int* in_sizes, int n_in,
                              void* d_out, int out_size, void* d_ws, size_t ws_size,
                              hipStream_t stream)
{
    const float* x   = (const float*)d_in[0];
    const float* pos = (const float*)d_in[1];
    const int*   ei  = (const int*)d_in[2];
    const float* ea  = (const float*)d_in[3];
    const float* Wm1 = (const float*)d_in[4];
    const float* bm1 = (const float*)d_in[5];
    const float* Wm2 = (const float*)d_in[6];
    const float* bm2 = (const float*)d_in[7];
    const float* Wn1 = (const float*)d_in[8];
    const float* bn1 = (const float*)d_in[9];
    const float* Wn2 = (const float*)d_in[10];
    const float* bn2 = (const float*)d_in[11];
    const float* Wc1 = (const float*)d_in[12];
    const float* bc1 = (const float*)d_in[13];
    const float* Wc2 = (const float*)d_in[14];
    const float* bc2 = (const float*)d_in[15];

    char* ws = (char*)d_ws;
    unsigned short* xb   = (unsigned short*)(ws);              // 12,800,000
    unsigned short* wt1  = (unsigned short*)(ws + 12800000);   //     65,536
    unsigned short* wt2  = (unsigned short*)(ws + 12865536);   //     32,768
    unsigned short* wtc1 = (unsigned short*)(ws + 12898304);   //     32,768
    unsigned short* wtn1 = (unsigned short*)(ws + 12931072);   //     65,536
    unsigned short* wtn2 = (unsigned short*)(ws + 12996608);   //     32,768
    // CSR-mode region
    int*   cnt    = (int*)(ws + 13029376);                     //    200,192
    int*   offs   = (int*)(ws + 13229568);                     //    200,192
    int*   offs2  = (int*)(ws + 13429760);                     //    200,192
    int*   slot   = (int*)(ws + 13629952);                     //  2,560,000
    float* wdiffv = (float*)(ws + 16189952);                   // 10,240,256
    unsigned short* msgb = (unsigned short*)(ws + 26430208);   // 163,840,000 -> 190,270,208
    // fallback-mode region (within round-1-proven 39.2 MB footprint)
    float* agg  = (float*)(ws + 13029376);                     // 25,600,000
    float* cagg = (float*)(ws + 38629376);                     //    600,000

    float* outx = (float*)d_out;
    float* outp = outx + (size_t)NN * HIDC;

    const bool useCSR = (ws_size >= (size_t)190270208);

    conv_x_kernel<<<25000, 256, 0, stream>>>(x, xb);
    conv_w_kernel<<<(114688 + 255) / 256, 256, 0, stream>>>(Wm1, Wm2, Wc1, Wn1, Wn2,
                                                            wt1, wt2, wtc1, wtn1, wtn2);
    if (useCSR) {
        hipMemsetAsync(cnt, 0, NN * sizeof(int), stream);
        count_kernel<<<2500, 256, 0, stream>>>(ei, cnt);
        scan_kernel<<<1, 1024, 0, stream>>>(cnt, offs, offs2);
        scatter_kernel<<<2500, 256, 0, stream>>>(ei, offs2, slot);
        edge_kernel<true><<<512, 512, 0, stream>>>(xb, pos, ei, ea, wt1, wt2, wtc1, Wm1,
                                                   bm1, bm2, bc1, Wc2, bc2,
                                                   slot, msgb, wdiffv, agg, cagg);
        node_kernel<true><<<NTILES, 512, 0, stream>>>(xb, msgb, wdiffv, offs, cnt,
                                                      agg, cagg, wtn1, wtn2, bn1, bn2,
                                                      pos, outx, outp);
    } else {
        hipMemsetAsync(agg, 0, (size_t)NN * HIDC * sizeof(float), stream);
        hipMemsetAsync(cagg, 0, (size_t)NN * 3 * sizeof(float), stream);
        edge_kernel<false><<<512, 512, 0, stream>>>(xb, pos, ei, ea, wt1, wt2, wtc1, Wm1,
                                                    bm1, bm2, bc1, Wc2, bc2,
                                                    slot, msgb, wdiffv, agg, cagg);
        node_kernel<false><<<NTILES, 512, 0, stream>>>(xb, msgb, wdiffv, offs, cnt,
                                                       agg, cagg, wtn1, wtn2, bn1, bn2,
                                                       pos, outx, outp);
    }
}